// Round 14
// baseline (411.697 us; speedup 1.0000x reference)
//
#include <hip/hip_runtime.h>
#include <hip/hip_bf16.h>

#define NN 100000     // nodes
#define NE 1600000    // edges before self loops
#define ET 1700000    // NE + NN
#define CH 128        // hidden channels (H*C, H=1)
#define NBC 391       // coarse buckets of 256 dst-nodes
#define PA_EPB 2048   // edges per block, phase A
#define BSTR 5376     // stage stride per bucket (mean 4352 + 15.5 sigma)

typedef unsigned int u32;
typedef unsigned short u16;
typedef unsigned char u8;

typedef __attribute__((ext_vector_type(8))) short bf16x8;
typedef __attribute__((ext_vector_type(4))) float f32x4;
typedef __attribute__((ext_vector_type(2))) float f32x2;

__device__ __forceinline__ float lo2f(u32 w) { return __uint_as_float(w << 16); }
__device__ __forceinline__ float hi2f(u32 w) { return __uint_as_float(w & 0xFFFF0000u); }
__device__ __forceinline__ u32 f2bits(float v) {
    __hip_bfloat16 t = __float2bfloat16(v);
    return (u32)*(u16*)&t;
}
__device__ __forceinline__ u32 pack2(float a, float b) {
    return (f2bits(b) << 16) | f2bits(a);
}
// fp8 e4m3 HW converts — word-select must be a compile-time constant
template<bool HI>
__device__ __forceinline__ int pk_fp8(float a, float b, int old) {
    return __builtin_amdgcn_cvt_pk_fp8_f32(a, b, old, HI);
}
template<bool HI>
__device__ __forceinline__ f32x2 unpk_fp8(u32 w) {
    return __builtin_amdgcn_cvt_pk_f32_fp8((int)w, HI);
}

// non-temporal (L2 no-allocate) streaming access
__device__ __forceinline__ int nt_ld(const int* p) { return __builtin_nontemporal_load(p); }
__device__ __forceinline__ float nt_ldf(const float* p) { return __builtin_nontemporal_load(p); }
__device__ __forceinline__ void nt_stf(float* p, float v) { __builtin_nontemporal_store(v, p); }

// ---------------------------------------------------------------------------
// Phase A: LDS-aggregated coarse bucketing into FIXED-stride bucket regions.
// ---------------------------------------------------------------------------
__global__ __launch_bounds__(256) void k_bucketA(
    const int* __restrict__ ei, const float* __restrict__ ew,
    u32* __restrict__ gcur, uint4* __restrict__ stage,
    u8* __restrict__ stage8, float* __restrict__ out_idx)
{
    __shared__ u32 hist[NBC];
    __shared__ u32 gbase[NBC];
    for (int i = threadIdx.x; i < NBC; i += 256) hist[i] = 0u;
    __syncthreads();
    int e0 = blockIdx.x * PA_EPB;
    int sA[8], dA[8], cbA[8];
    float w0A[8], w1A[8];
    u32 rkA[8];
#pragma unroll
    for (int i = 0; i < 8; ++i) {
        int e = e0 + i * 256 + threadIdx.x;
        int s = 0, d = 0; float w0 = 0.f, w1 = 0.f;
        if (e < ET) {
            if (e < NE) {
                s = nt_ld(ei + e); d = nt_ld(ei + NE + e);
                w0 = nt_ldf(ew + 2 * e); w1 = nt_ldf(ew + 2 * e + 1);
            } else { s = d = e - NE; }
            nt_stf(out_idx + e,      (float)s);
            nt_stf(out_idx + ET + e, (float)d);
            if ((u32)d >= NN) d = 0;
            if ((u32)s >= NN) s = 0;
            int cb = d >> 8;
            rkA[i] = atomicAdd(&hist[cb], 1u);
            cbA[i] = cb;
        } else cbA[i] = -1;
        sA[i] = s; dA[i] = d; w0A[i] = w0; w1A[i] = w1;
    }
    __syncthreads();
    for (int i = threadIdx.x; i < NBC; i += 256) {
        u32 h = hist[i];
        gbase[i] = h ? atomicAdd(&gcur[i * 16], h) : 0u;   // 64B-padded cursors
    }
    __syncthreads();
#pragma unroll
    for (int i = 0; i < 8; ++i) {
        if (cbA[i] < 0) continue;
        int e = e0 + i * 256 + threadIdx.x;
        u32 pos = (u32)cbA[i] * BSTR + gbase[cbA[i]] + rkA[i];
        stage[pos]  = make_uint4((u32)sA[i], pack2(w0A[i], w1A[i]), (u32)e, (u32)dA[i]);
        stage8[pos] = (u8)(dA[i] & 255);
    }
}

// ---------------------------------------------------------------------------
// scanG: one block scans the 391 bucket totals (gcur) -> bucket bases (bbase).
// ---------------------------------------------------------------------------
__global__ __launch_bounds__(512) void k_scanG(
    const u32* __restrict__ gcur, u32* __restrict__ bbase,
    u32* __restrict__ rowptr)
{
    __shared__ u32 s[512];
    int t = threadIdx.x;
    u32 v = (t < NBC) ? gcur[t * 16] : 0u;
    s[t] = v; __syncthreads();
    for (int off = 1; off < 512; off <<= 1) {
        u32 a = (t >= off) ? s[t - off] : 0u;
        __syncthreads();
        s[t] += a;
        __syncthreads();
    }
    if (t < NBC) bbase[t] = s[t] - v;    // exclusive bucket base
    if (t == 0) rowptr[NN] = ET;
}

// ---------------------------------------------------------------------------
// Phase B: one block per bucket; histogram -> rowptr -> scatter.
// ---------------------------------------------------------------------------
__global__ __launch_bounds__(256) void k_bucketB(
    const u32* __restrict__ gcur, const u32* __restrict__ bbase,
    const uint4* __restrict__ stage, const u8* __restrict__ stage8,
    u32* __restrict__ rowptr, uint4* __restrict__ erec)
{
    __shared__ u32 hist[256];
    __shared__ u32 cur[256];
    int b = blockIdx.x;
    u32 cnt_b = gcur[b * 16];
    u32 bb = bbase[b];
    const uint4* sb = stage + (size_t)b * BSTR;
    const u8*    s8 = stage8 + (size_t)b * BSTR;

    hist[threadIdx.x] = 0u;
    __syncthreads();
    for (u32 p = threadIdx.x; p < cnt_b; p += 256)
        atomicAdd(&hist[s8[p]], 1u);
    __syncthreads();
    u32 v = hist[threadIdx.x];
    for (int off = 1; off < 256; off <<= 1) {
        u32 a = (threadIdx.x >= off) ? hist[threadIdx.x - off] : 0u;
        __syncthreads();
        hist[threadIdx.x] += a;
        __syncthreads();
    }
    u32 start = bb + hist[threadIdx.x] - v;    // exclusive
    int n = (b << 8) + threadIdx.x;
    if (n < NN) rowptr[n] = start;
    cur[threadIdx.x] = start;
    __syncthreads();
    for (u32 p = threadIdx.x; p < cnt_b; p += 256) {
        uint4 r = sb[p];
        u32 slot = atomicAdd(&cur[r.w & 255], 1u);
        erec[slot] = make_uint4(r.x, r.y, r.z, 0u);
    }
}

// ---------------------------------------------------------------------------
// k_pre: xl = x@Wl+bl -> fp8 (128 B/row); xr = x@Wr+br -> bf16 (256 B/row)
// ---------------------------------------------------------------------------
__global__ __launch_bounds__(256) void k_pre(
    const float* __restrict__ x,
    const float* __restrict__ Wl, const float* __restrict__ bl,
    const float* __restrict__ Wr, const float* __restrict__ br,
    u32* __restrict__ xl8, uint2* __restrict__ xrh)
{
    __shared__ float sWl[6][CH], sWr[6][CH], sbl[CH], sbr[CH];
    for (int i = threadIdx.x; i < 6 * CH; i += 256) {
        sWl[i / CH][i % CH] = Wl[i];
        sWr[i / CH][i % CH] = Wr[i];
    }
    for (int i = threadIdx.x; i < CH; i += 256) { sbl[i] = bl[i]; sbr[i] = br[i]; }
    __syncthreads();

    int tid = blockIdx.x * 256 + threadIdx.x;   // grid covers NN*32 exactly
    int n = tid >> 5, q = tid & 31, c0 = q * 4;
    float xs[6];
#pragma unroll
    for (int k = 0; k < 6; ++k) xs[k] = x[n * 6 + k];
    float l[4], r[4];
#pragma unroll
    for (int j = 0; j < 4; ++j) { l[j] = sbl[c0 + j]; r[j] = sbr[c0 + j]; }
#pragma unroll
    for (int k = 0; k < 6; ++k)
#pragma unroll
        for (int j = 0; j < 4; ++j) {
            l[j] += xs[k] * sWl[k][c0 + j];
            r[j] += xs[k] * sWr[k][c0 + j];
        }
    int v = pk_fp8<false>(l[0], l[1], 0);
    v = pk_fp8<true>(l[2], l[3], v);
    xl8[tid] = (u32)v;                               // bytes = channels c0..c0+3
    xrh[tid] = make_uint2(pack2(r[0], r[1]), pack2(r[2], r[3]));
}

// ---------------------------------------------------------------------------
// k_fused (wave/node; 4 edge-groups of 16 lanes x 8 channels), depth-2
// software pipeline — round-3 verified body (121.5 µs, 48 VGPR, occ 47.5%).
// DO NOT TOUCH: r6/r7/r9/r10/r12 all regressed or washed. 48 VGPR is the
// last slot in the good occupancy tier (64-VGPR allocation granularity).
// ---------------------------------------------------------------------------
__global__ __launch_bounds__(256) void k_fused(
    const u32* __restrict__ rowptr, uint4* erec,
    const u32* __restrict__ xl8,
    const float* __restrict__ We, const float* __restrict__ att,
    const float* __restrict__ bgat,
    uint4* xr,                        // in: xr bf16 ; out: h bf16 (in place)
    float* __restrict__ den_g)
{
    int n = (blockIdx.x << 2) + (threadIdx.x >> 6);   // grid: NN/4
    int lane = threadIdx.x & 63;
    int g = lane >> 4;            // edge-group 0..3
    int gl = lane & 15;           // lane in group
    int c0 = gl * 8;              // 8 channels per lane

    float we0[8], we1[8], at[8];
#pragma unroll
    for (int j = 0; j < 8; ++j) {
        we0[j] = We[c0 + j];
        we1[j] = We[CH + c0 + j];
        at[j]  = att[c0 + j];
    }

    uint4 xw = xr[(size_t)n * 16 + gl];   // 8 bf16 channels
    float xrv[8] = {lo2f(xw.x), hi2f(xw.x), lo2f(xw.y), hi2f(xw.y),
                    lo2f(xw.z), hi2f(xw.z), lo2f(xw.w), hi2f(xw.w)};

    u32 p0 = rowptr[n], p1 = rowptr[n + 1];
    u32 last = p1 - 1;                    // >= p0 (self-loop guarantees >=1)
    float den = 0.f;
    float num[8] = {0.f, 0.f, 0.f, 0.f, 0.f, 0.f, 0.f, 0.f};

    u32 p = p0 + g;
    uint4 er0 = erec[p <= last ? p : last];
    uint4 er1 = erec[p + 4 <= last ? p + 4 : last];
    uint2 w0 = ((const uint2*)xl8)[(size_t)er0.x * 16 + gl];

    for (; p < p1; p += 4) {
        uint4 er2 = erec[p + 8 <= last ? p + 8 : last];             // prefetch
        uint2 w1 = ((const uint2*)xl8)[(size_t)er1.x * 16 + gl];    // prefetch
        float ea0 = lo2f(er0.y), ea1 = hi2f(er0.y);
        f32x2 d0 = unpk_fp8<false>(w0.x), d1 = unpk_fp8<true>(w0.x);
        f32x2 d2 = unpk_fp8<false>(w0.y), d3 = unpk_fp8<true>(w0.y);
        float xl[8] = {d0.x, d0.y, d1.x, d1.y, d2.x, d2.y, d3.x, d3.y};
        float s = 0.f;
#pragma unroll
        for (int j = 0; j < 8; ++j) {
            float z = xl[j] + xrv[j] + ea0 * we0[j] + ea1 * we1[j];
            z = z > 0.f ? z : 0.2f * z;         // leaky_relu(0.2)
            s += z * at[j];
        }
        s += __shfl_xor(s, 1, 64);
        s += __shfl_xor(s, 2, 64);
        s += __shfl_xor(s, 4, 64);
        s += __shfl_xor(s, 8, 64);              // all 16 lanes hold s
        s = fminf(fmaxf(s, -60.f), 60.f);
        float ex = __expf(s);
        den += ex;
#pragma unroll
        for (int j = 0; j < 8; ++j) num[j] += ex * xl[j];
        if (gl == 0) erec[p].w = __float_as_uint(ex);
        er0 = er1; er1 = er2; w0 = w1;
    }
    // cross-group merge
    den += __shfl_xor(den, 16, 64);
    den += __shfl_xor(den, 32, 64);
#pragma unroll
    for (int j = 0; j < 8; ++j) {
        num[j] += __shfl_xor(num[j], 16, 64);
        num[j] += __shfl_xor(num[j], 32, 64);
    }
    float rden = (den > 1e-30f) ? 1.f / den : 0.f;
    if (lane == 0) den_g[n] = den;
    if (g == 0) {
        float r[8];
#pragma unroll
        for (int j = 0; j < 8; ++j) {
            float v = num[j] * rden + bgat[c0 + j];
            r[j] = v > 0.f ? v : 0.f;
        }
        xr[(size_t)n * 16 + gl] = make_uint4(pack2(r[0], r[1]), pack2(r[2], r[3]),
                                             pack2(r[4], r[5]), pack2(r[6], r[7]));
    }
}

// ---------------------------------------------------------------------------
// GEMM1 (MFMA): hg = h @ W2; h bf16 rows (256 B), hg -> fp8 rows (128 B).
// ---------------------------------------------------------------------------
__global__ __launch_bounds__(256) void k_gemm1(
    const u32* __restrict__ hb, const float* __restrict__ W2,
    uint2* __restrict__ hg8)
{
    int lane = threadIdx.x & 63;
    int wv = threadIdx.x >> 6;
    int quad = lane >> 4;
    int l15 = lane & 15;

    // B fragments [kc][n0], once per block (W2 is L2-hot)
    bf16x8 bfrag[4][8];
#pragma unroll
    for (int kc = 0; kc < 4; ++kc) {
#pragma unroll
        for (int n0 = 0; n0 < 8; ++n0) {
            int kbase = kc * 32 + quad * 8;
            int col = n0 * 16 + l15;
            union { bf16x8 v; u32 u[4]; } t;
#pragma unroll
            for (int jj = 0; jj < 4; ++jj) {
                float w0 = W2[(kbase + 2 * jj) * CH + col];
                float w1 = W2[(kbase + 2 * jj + 1) * CH + col];
                t.u[jj] = pack2(w0, w1);
            }
            bfrag[kc][n0] = t.v;
        }
    }

    const int nchunk = (NN + 63) / 64;       // 1563
    for (int ch = blockIdx.x; ch < nchunk; ch += gridDim.x) {
        int m0 = ch * 64 + wv * 16;
        int arow = m0 + l15;
        if (arow >= NN) arow = NN - 1;       // clamp (stores guarded)
        const uint4* ap = (const uint4*)(hb + (size_t)arow * 64);

        bf16x8 afrag[4];
#pragma unroll
        for (int kc = 0; kc < 4; ++kc) {
            union { uint4 q; bf16x8 v; } t;
            t.q = ap[kc * 4 + quad];
            afrag[kc] = t.v;
        }

        f32x4 acc[8];
#pragma unroll
        for (int n0 = 0; n0 < 8; ++n0) acc[n0] = (f32x4){0.f, 0.f, 0.f, 0.f};
#pragma unroll
        for (int n0 = 0; n0 < 8; ++n0)
#pragma unroll
            for (int kc = 0; kc < 4; ++kc)
                acc[n0] = __builtin_amdgcn_mfma_f32_16x16x32_bf16(
                    afrag[kc], bfrag[kc][n0], acc[n0], 0, 0, 0);

#pragma unroll
        for (int r = 0; r < 4; ++r) {
            int row = m0 + quad * 4 + r;
            if (row < NN) {
                int a = pk_fp8<false>(acc[0][r], acc[1][r], 0);
                a = pk_fp8<true>(acc[2][r], acc[3][r], a);
                int b = pk_fp8<false>(acc[4][r], acc[5][r], 0);
                b = pk_fp8<true>(acc[6][r], acc[7][r], b);
                hg8[(size_t)row * 16 + l15] = make_uint2((u32)a, (u32)b);
            }
        }
    }
}

// ---------------------------------------------------------------------------
// k_h2f (wave/node; 4 edge-groups of 16), UNROLL x4 + LDS constants:
// per iteration each group processes edges p, p+4, p+8, p+12, holding 8 erec
// records + 4 hg8 gathers in flight (2x the r10 unroll-x2 MLP). Small
// per-edge state makes the extra pipeline registers affordable here (unlike
// k_fused). Clamped prefetch (r12: clamp-free inflates FETCH).
// ---------------------------------------------------------------------------
__global__ __launch_bounds__(256) void k_h2f(
    const u32* __restrict__ rowptr, const uint4* __restrict__ erec,
    const float* __restrict__ den_g, const uint2* __restrict__ hg8,
    const float* __restrict__ bgcn, const float* __restrict__ W3,
    const float* __restrict__ b3,
    float* __restrict__ out_alpha, float* __restrict__ out)
{
    __shared__ float sW30[CH], sW31[CH], sBg[CH];
    for (int i = threadIdx.x; i < CH; i += 256) {
        sW30[i] = W3[2 * i];
        sW31[i] = W3[2 * i + 1];
        sBg[i]  = bgcn[i];
    }
    __syncthreads();

    int n = (blockIdx.x << 2) + (threadIdx.x >> 6);
    int lane = threadIdx.x & 63;
    int g = lane >> 4;
    int gl = lane & 15;

    float dn = den_g[n];
    float rden = (dn > 1e-30f) ? 1.f / dn : 0.f;
    u32 p0 = rowptr[n], p1 = rowptr[n + 1];
    u32 last = p1 - 1;
    float acc[8] = {0.f, 0.f, 0.f, 0.f, 0.f, 0.f, 0.f, 0.f};

#define CL(k) ((p + (k)) <= last ? (p + (k)) : last)
    u32 p = p0 + g;
    uint4 erA = erec[CL(0)],  erB = erec[CL(4)],  erC = erec[CL(8)],  erD = erec[CL(12)];
    uint4 erE = erec[CL(16)], erF = erec[CL(20)], erG = erec[CL(24)], erH = erec[CL(28)];
    uint2 wA = hg8[(size_t)erA.x * 16 + gl];
    uint2 wB = hg8[(size_t)erB.x * 16 + gl];
    uint2 wC = hg8[(size_t)erC.x * 16 + gl];
    uint2 wD = hg8[(size_t)erD.x * 16 + gl];

    for (; p < p1; p += 16) {
        uint4 erI = erec[CL(32)], erJ = erec[CL(36)];       // prefetch (2 ahead)
        uint4 erK = erec[CL(40)], erL = erec[CL(44)];
        uint2 wE = hg8[(size_t)erE.x * 16 + gl];            // gathers (1 ahead)
        uint2 wF = hg8[(size_t)erF.x * 16 + gl];
        uint2 wG = hg8[(size_t)erG.x * 16 + gl];
        uint2 wH = hg8[(size_t)erH.x * 16 + gl];

        // ---- edge A (p, always valid) ----
        {
            float a = __uint_as_float(erA.w) * rden;
            if (gl == 0) nt_stf(out_alpha + erA.z, a);
            f32x2 d0 = unpk_fp8<false>(wA.x), d1 = unpk_fp8<true>(wA.x);
            f32x2 d2 = unpk_fp8<false>(wA.y), d3 = unpk_fp8<true>(wA.y);
            acc[0] += a * d0.x; acc[1] += a * d0.y;
            acc[2] += a * d1.x; acc[3] += a * d1.y;
            acc[4] += a * d2.x; acc[5] += a * d2.y;
            acc[6] += a * d3.x; acc[7] += a * d3.y;
        }
        // ---- edge B (p+4, guarded) ----
        {
            bool v = (p + 4) < p1;
            float a = __uint_as_float(erB.w) * rden;
            a = v ? a : 0.f;
            if (gl == 0 && v) nt_stf(out_alpha + erB.z, a);
            f32x2 d0 = unpk_fp8<false>(wB.x), d1 = unpk_fp8<true>(wB.x);
            f32x2 d2 = unpk_fp8<false>(wB.y), d3 = unpk_fp8<true>(wB.y);
            acc[0] += a * d0.x; acc[1] += a * d0.y;
            acc[2] += a * d1.x; acc[3] += a * d1.y;
            acc[4] += a * d2.x; acc[5] += a * d2.y;
            acc[6] += a * d3.x; acc[7] += a * d3.y;
        }
        // ---- edge C (p+8, guarded) ----
        {
            bool v = (p + 8) < p1;
            float a = __uint_as_float(erC.w) * rden;
            a = v ? a : 0.f;
            if (gl == 0 && v) nt_stf(out_alpha + erC.z, a);
            f32x2 d0 = unpk_fp8<false>(wC.x), d1 = unpk_fp8<true>(wC.x);
            f32x2 d2 = unpk_fp8<false>(wC.y), d3 = unpk_fp8<true>(wC.y);
            acc[0] += a * d0.x; acc[1] += a * d0.y;
            acc[2] += a * d1.x; acc[3] += a * d1.y;
            acc[4] += a * d2.x; acc[5] += a * d2.y;
            acc[6] += a * d3.x; acc[7] += a * d3.y;
        }
        // ---- edge D (p+12, guarded) ----
        {
            bool v = (p + 12) < p1;
            float a = __uint_as_float(erD.w) * rden;
            a = v ? a : 0.f;
            if (gl == 0 && v) nt_stf(out_alpha + erD.z, a);
            f32x2 d0 = unpk_fp8<false>(wD.x), d1 = unpk_fp8<true>(wD.x);
            f32x2 d2 = unpk_fp8<false>(wD.y), d3 = unpk_fp8<true>(wD.y);
            acc[0] += a * d0.x; acc[1] += a * d0.y;
            acc[2] += a * d1.x; acc[3] += a * d1.y;
            acc[4] += a * d2.x; acc[5] += a * d2.y;
            acc[6] += a * d3.x; acc[7] += a * d3.y;
        }
        erA = erE; erB = erF; erC = erG; erD = erH;
        erE = erI; erF = erJ; erG = erK; erH = erL;
        wA = wE; wB = wF; wC = wG; wD = wH;
    }
#undef CL
#pragma unroll
    for (int j = 0; j < 8; ++j) {
        acc[j] += __shfl_xor(acc[j], 16, 64);
        acc[j] += __shfl_xor(acc[j], 32, 64);
    }
    float o0 = 0.f, o1 = 0.f;
#pragma unroll
    for (int j = 0; j < 8; ++j) {
        int c = 16 * j + gl;
        float v = acc[j] + sBg[c];
        v = v > 0.f ? v : 0.f;
        o0 += v * sW30[c];
        o1 += v * sW31[c];
    }
    o0 += __shfl_xor(o0, 1, 64); o1 += __shfl_xor(o1, 1, 64);
    o0 += __shfl_xor(o0, 2, 64); o1 += __shfl_xor(o1, 2, 64);
    o0 += __shfl_xor(o0, 4, 64); o1 += __shfl_xor(o1, 4, 64);
    o0 += __shfl_xor(o0, 8, 64); o1 += __shfl_xor(o1, 8, 64);
    if (lane == 0) {
        out[n * 2]     = o0 + b3[0];
        out[n * 2 + 1] = o1 + b3[1];
    }
}

// ---------------------------------------------------------------------------
extern "C" void kernel_launch(void* const* d_in, const int* in_sizes, int n_in,
                              void* d_out, int out_size, void* d_ws, size_t ws_size,
                              hipStream_t stream)
{
    const float* x    = (const float*)d_in[0];
    const int*   ei   = (const int*)d_in[1];
    const float* ew   = (const float*)d_in[2];
    const float* Wl   = (const float*)d_in[3];
    const float* bl   = (const float*)d_in[4];
    const float* Wr   = (const float*)d_in[5];
    const float* br   = (const float*)d_in[6];
    const float* We   = (const float*)d_in[7];
    const float* att  = (const float*)d_in[8];
    const float* bgat = (const float*)d_in[9];
    const float* W2   = (const float*)d_in[10];
    const float* bgcn = (const float*)d_in[11];
    const float* W3   = (const float*)d_in[12];
    const float* b3   = (const float*)d_in[13];

    float* out       = (float*)d_out;          // chunk0: out [N,2] f32
    float* out_idx   = out + 200000;           // chunk1: stack([src,dst]) [2,ET]
    float* out_alpha = out + 200000 + 2 * ET;  // chunk2: alpha [ET,1]

    // workspace (~66.5 MB):
    // xl8 u32[NN*32] (fp8 xl; later hg8 fp8)  | xrh uint2[NN*32] (bf16 xr -> h)
    // | erec uint4[ET] | den f32[NN] | gcur u32[NBC*16] | rowptr[NN+1] | bbase[512]
    // stage uint4[NBC*BSTR] (33.6MB) + stage8 u8[NBC*BSTR] (2.1MB) alias
    // xl8+xrh (38.4MB), consumed by k_bucketB before k_pre writes.
    u32*   xl8    = (u32*)d_ws;
    uint2* xrh    = (uint2*)(xl8 + (size_t)NN * 32);
    uint4* erec   = (uint4*)(xrh + (size_t)NN * 32);
    float* den    = (float*)(erec + ET);
    u32*   gcur   = (u32*)den + NN;
    u32*   rowptr = gcur + NBC * 16;
    u32*   bbase  = rowptr + NN + 1;
    uint4* stage  = (uint4*)d_ws;                       // alias: xl8/xrh region
    u8*    stage8 = (u8*)d_ws + (size_t)NBC * BSTR * 16;  // after stage, still in alias

    const int AB = (ET + PA_EPB - 1) / PA_EPB; // 831

    // --- CSR build (+ out_idx): bucketA -> scanG -> bucketB (writes rowptr) ---
    (void)hipMemsetAsync(gcur, 0, NBC * 16 * sizeof(u32), stream);
    k_bucketA<<<AB, 256, 0, stream>>>(ei, ew, gcur, stage, stage8, out_idx);
    k_scanG<<<1, 512, 0, stream>>>(gcur, bbase, rowptr);
    k_bucketB<<<NBC, 256, 0, stream>>>(gcur, bbase, stage, stage8, rowptr, erec);

    // --- projections + fused attention/aggregation ---
    k_pre<<<(NN * 32) / 256, 256, 0, stream>>>(x, Wl, bl, Wr, br, xl8, xrh);
    k_fused<<<NN / 4, 256, 0, stream>>>(rowptr, erec, xl8, We, att, bgat,
                                        (uint4*)xrh, den);

    // --- GCN (MFMA, fp8 out) + fused h2+MLP ---
    k_gemm1<<<512, 256, 0, stream>>>((const u32*)xrh, W2, (uint2*)xl8);
    k_h2f<<<NN / 4, 256, 0, stream>>>(rowptr, erec, den, (const uint2*)xl8,
                                      bgcn, W3, b3, out_alpha, out);
}

// Round 15
// 391.502 us; speedup vs baseline: 1.0516x; 1.0516x over previous
//
#include <hip/hip_runtime.h>
#include <hip/hip_bf16.h>

#define NN 100000     // nodes
#define NE 1600000    // edges before self loops
#define ET 1700000    // NE + NN
#define CH 128        // hidden channels (H*C, H=1)
#define NBC 391       // coarse buckets of 256 dst-nodes
#define PA_EPB 2048   // edges per block, phase A
#define BSTR 5376     // stage stride per bucket (mean 4352 + 15.5 sigma)

typedef unsigned int u32;
typedef unsigned short u16;
typedef unsigned char u8;

typedef __attribute__((ext_vector_type(8))) short bf16x8;
typedef __attribute__((ext_vector_type(4))) float f32x4;
typedef __attribute__((ext_vector_type(2))) float f32x2;
typedef __attribute__((ext_vector_type(4))) u32 u32x4;

__device__ __forceinline__ float lo2f(u32 w) { return __uint_as_float(w << 16); }
__device__ __forceinline__ float hi2f(u32 w) { return __uint_as_float(w & 0xFFFF0000u); }
__device__ __forceinline__ u32 f2bits(float v) {
    __hip_bfloat16 t = __float2bfloat16(v);
    return (u32)*(u16*)&t;
}
__device__ __forceinline__ u32 pack2(float a, float b) {
    return (f2bits(b) << 16) | f2bits(a);
}
// fp8 e4m3 HW converts — word-select must be a compile-time constant
template<bool HI>
__device__ __forceinline__ int pk_fp8(float a, float b, int old) {
    return __builtin_amdgcn_cvt_pk_fp8_f32(a, b, old, HI);
}
template<bool HI>
__device__ __forceinline__ f32x2 unpk_fp8(u32 w) {
    return __builtin_amdgcn_cvt_pk_f32_fp8((int)w, HI);
}

// non-temporal (L2 no-allocate) streaming access
__device__ __forceinline__ int nt_ld(const int* p) { return __builtin_nontemporal_load(p); }
__device__ __forceinline__ float nt_ldf(const float* p) { return __builtin_nontemporal_load(p); }
__device__ __forceinline__ void nt_stf(float* p, float v) { __builtin_nontemporal_store(v, p); }
__device__ __forceinline__ uint4 nt_ld4(const uint4* p) {
    u32x4 v = __builtin_nontemporal_load((const u32x4*)p);
    return make_uint4(v.x, v.y, v.z, v.w);
}

// ---------------------------------------------------------------------------
// Phase A: LDS-aggregated coarse bucketing into FIXED-stride bucket regions.
// ---------------------------------------------------------------------------
__global__ __launch_bounds__(256) void k_bucketA(
    const int* __restrict__ ei, const float* __restrict__ ew,
    u32* __restrict__ gcur, uint4* __restrict__ stage,
    u8* __restrict__ stage8, float* __restrict__ out_idx)
{
    __shared__ u32 hist[NBC];
    __shared__ u32 gbase[NBC];
    for (int i = threadIdx.x; i < NBC; i += 256) hist[i] = 0u;
    __syncthreads();
    int e0 = blockIdx.x * PA_EPB;
    int sA[8], dA[8], cbA[8];
    float w0A[8], w1A[8];
    u32 rkA[8];
#pragma unroll
    for (int i = 0; i < 8; ++i) {
        int e = e0 + i * 256 + threadIdx.x;
        int s = 0, d = 0; float w0 = 0.f, w1 = 0.f;
        if (e < ET) {
            if (e < NE) {
                s = nt_ld(ei + e); d = nt_ld(ei + NE + e);
                w0 = nt_ldf(ew + 2 * e); w1 = nt_ldf(ew + 2 * e + 1);
            } else { s = d = e - NE; }
            nt_stf(out_idx + e,      (float)s);
            nt_stf(out_idx + ET + e, (float)d);
            if ((u32)d >= NN) d = 0;
            if ((u32)s >= NN) s = 0;
            int cb = d >> 8;
            rkA[i] = atomicAdd(&hist[cb], 1u);
            cbA[i] = cb;
        } else cbA[i] = -1;
        sA[i] = s; dA[i] = d; w0A[i] = w0; w1A[i] = w1;
    }
    __syncthreads();
    for (int i = threadIdx.x; i < NBC; i += 256) {
        u32 h = hist[i];
        gbase[i] = h ? atomicAdd(&gcur[i * 16], h) : 0u;   // 64B-padded cursors
    }
    __syncthreads();
#pragma unroll
    for (int i = 0; i < 8; ++i) {
        if (cbA[i] < 0) continue;
        int e = e0 + i * 256 + threadIdx.x;
        u32 pos = (u32)cbA[i] * BSTR + gbase[cbA[i]] + rkA[i];
        stage[pos]  = make_uint4((u32)sA[i], pack2(w0A[i], w1A[i]), (u32)e, (u32)dA[i]);
        stage8[pos] = (u8)(dA[i] & 255);
    }
}

// ---------------------------------------------------------------------------
// scanG: one block scans the 391 bucket totals (gcur) -> bucket bases (bbase).
// ---------------------------------------------------------------------------
__global__ __launch_bounds__(512) void k_scanG(
    const u32* __restrict__ gcur, u32* __restrict__ bbase,
    u32* __restrict__ rowptr)
{
    __shared__ u32 s[512];
    int t = threadIdx.x;
    u32 v = (t < NBC) ? gcur[t * 16] : 0u;
    s[t] = v; __syncthreads();
    for (int off = 1; off < 512; off <<= 1) {
        u32 a = (t >= off) ? s[t - off] : 0u;
        __syncthreads();
        s[t] += a;
        __syncthreads();
    }
    if (t < NBC) bbase[t] = s[t] - v;    // exclusive bucket base
    if (t == 0) rowptr[NN] = ET;
}

// ---------------------------------------------------------------------------
// Phase B: one block per bucket; histogram -> rowptr -> scatter.
// ---------------------------------------------------------------------------
__global__ __launch_bounds__(256) void k_bucketB(
    const u32* __restrict__ gcur, const u32* __restrict__ bbase,
    const uint4* __restrict__ stage, const u8* __restrict__ stage8,
    u32* __restrict__ rowptr, uint4* __restrict__ erec)
{
    __shared__ u32 hist[256];
    __shared__ u32 cur[256];
    int b = blockIdx.x;
    u32 cnt_b = gcur[b * 16];
    u32 bb = bbase[b];
    const uint4* sb = stage + (size_t)b * BSTR;
    const u8*    s8 = stage8 + (size_t)b * BSTR;

    hist[threadIdx.x] = 0u;
    __syncthreads();
    for (u32 p = threadIdx.x; p < cnt_b; p += 256)
        atomicAdd(&hist[s8[p]], 1u);
    __syncthreads();
    u32 v = hist[threadIdx.x];
    for (int off = 1; off < 256; off <<= 1) {
        u32 a = (threadIdx.x >= off) ? hist[threadIdx.x - off] : 0u;
        __syncthreads();
        hist[threadIdx.x] += a;
        __syncthreads();
    }
    u32 start = bb + hist[threadIdx.x] - v;    // exclusive
    int n = (b << 8) + threadIdx.x;
    if (n < NN) rowptr[n] = start;
    cur[threadIdx.x] = start;
    __syncthreads();
    for (u32 p = threadIdx.x; p < cnt_b; p += 256) {
        uint4 r = sb[p];
        u32 slot = atomicAdd(&cur[r.w & 255], 1u);
        erec[slot] = make_uint4(r.x, r.y, r.z, 0u);
    }
}

// ---------------------------------------------------------------------------
// k_pre: xl = x@Wl+bl -> fp8 (128 B/row); xr = x@Wr+br -> bf16 (256 B/row)
// ---------------------------------------------------------------------------
__global__ __launch_bounds__(256) void k_pre(
    const float* __restrict__ x,
    const float* __restrict__ Wl, const float* __restrict__ bl,
    const float* __restrict__ Wr, const float* __restrict__ br,
    u32* __restrict__ xl8, uint2* __restrict__ xrh)
{
    __shared__ float sWl[6][CH], sWr[6][CH], sbl[CH], sbr[CH];
    for (int i = threadIdx.x; i < 6 * CH; i += 256) {
        sWl[i / CH][i % CH] = Wl[i];
        sWr[i / CH][i % CH] = Wr[i];
    }
    for (int i = threadIdx.x; i < CH; i += 256) { sbl[i] = bl[i]; sbr[i] = br[i]; }
    __syncthreads();

    int tid = blockIdx.x * 256 + threadIdx.x;   // grid covers NN*32 exactly
    int n = tid >> 5, q = tid & 31, c0 = q * 4;
    float xs[6];
#pragma unroll
    for (int k = 0; k < 6; ++k) xs[k] = x[n * 6 + k];
    float l[4], r[4];
#pragma unroll
    for (int j = 0; j < 4; ++j) { l[j] = sbl[c0 + j]; r[j] = sbr[c0 + j]; }
#pragma unroll
    for (int k = 0; k < 6; ++k)
#pragma unroll
        for (int j = 0; j < 4; ++j) {
            l[j] += xs[k] * sWl[k][c0 + j];
            r[j] += xs[k] * sWr[k][c0 + j];
        }
    int v = pk_fp8<false>(l[0], l[1], 0);
    v = pk_fp8<true>(l[2], l[3], v);
    xl8[tid] = (u32)v;                               // bytes = channels c0..c0+3
    xrh[tid] = make_uint2(pack2(r[0], r[1]), pack2(r[2], r[3]));
}

// ---------------------------------------------------------------------------
// k_fused (wave/node; 4 edge-groups of 16 lanes x 8 channels), depth-2
// software pipeline — round-3 verified body (121.5 µs, 48 VGPR, occ 47.5%).
// DO NOT TOUCH: r6/r7/r9/r10/r12 all regressed or washed. 48 VGPR is the
// last slot in the good occupancy tier.
// ---------------------------------------------------------------------------
__global__ __launch_bounds__(256) void k_fused(
    const u32* __restrict__ rowptr, uint4* erec,
    const u32* __restrict__ xl8,
    const float* __restrict__ We, const float* __restrict__ att,
    const float* __restrict__ bgat,
    uint4* xr,                        // in: xr bf16 ; out: h bf16 (in place)
    float* __restrict__ den_g)
{
    int n = (blockIdx.x << 2) + (threadIdx.x >> 6);   // grid: NN/4
    int lane = threadIdx.x & 63;
    int g = lane >> 4;            // edge-group 0..3
    int gl = lane & 15;           // lane in group
    int c0 = gl * 8;              // 8 channels per lane

    float we0[8], we1[8], at[8];
#pragma unroll
    for (int j = 0; j < 8; ++j) {
        we0[j] = We[c0 + j];
        we1[j] = We[CH + c0 + j];
        at[j]  = att[c0 + j];
    }

    uint4 xw = xr[(size_t)n * 16 + gl];   // 8 bf16 channels
    float xrv[8] = {lo2f(xw.x), hi2f(xw.x), lo2f(xw.y), hi2f(xw.y),
                    lo2f(xw.z), hi2f(xw.z), lo2f(xw.w), hi2f(xw.w)};

    u32 p0 = rowptr[n], p1 = rowptr[n + 1];
    u32 last = p1 - 1;                    // >= p0 (self-loop guarantees >=1)
    float den = 0.f;
    float num[8] = {0.f, 0.f, 0.f, 0.f, 0.f, 0.f, 0.f, 0.f};

    u32 p = p0 + g;
    uint4 er0 = erec[p <= last ? p : last];
    uint4 er1 = erec[p + 4 <= last ? p + 4 : last];
    uint2 w0 = ((const uint2*)xl8)[(size_t)er0.x * 16 + gl];

    for (; p < p1; p += 4) {
        uint4 er2 = erec[p + 8 <= last ? p + 8 : last];             // prefetch
        uint2 w1 = ((const uint2*)xl8)[(size_t)er1.x * 16 + gl];    // prefetch
        float ea0 = lo2f(er0.y), ea1 = hi2f(er0.y);
        f32x2 d0 = unpk_fp8<false>(w0.x), d1 = unpk_fp8<true>(w0.x);
        f32x2 d2 = unpk_fp8<false>(w0.y), d3 = unpk_fp8<true>(w0.y);
        float xl[8] = {d0.x, d0.y, d1.x, d1.y, d2.x, d2.y, d3.x, d3.y};
        float s = 0.f;
#pragma unroll
        for (int j = 0; j < 8; ++j) {
            float z = xl[j] + xrv[j] + ea0 * we0[j] + ea1 * we1[j];
            z = z > 0.f ? z : 0.2f * z;         // leaky_relu(0.2)
            s += z * at[j];
        }
        s += __shfl_xor(s, 1, 64);
        s += __shfl_xor(s, 2, 64);
        s += __shfl_xor(s, 4, 64);
        s += __shfl_xor(s, 8, 64);              // all 16 lanes hold s
        s = fminf(fmaxf(s, -60.f), 60.f);
        float ex = __expf(s);
        den += ex;
#pragma unroll
        for (int j = 0; j < 8; ++j) num[j] += ex * xl[j];
        if (gl == 0) erec[p].w = __float_as_uint(ex);
        er0 = er1; er1 = er2; w0 = w1;
    }
    // cross-group merge
    den += __shfl_xor(den, 16, 64);
    den += __shfl_xor(den, 32, 64);
#pragma unroll
    for (int j = 0; j < 8; ++j) {
        num[j] += __shfl_xor(num[j], 16, 64);
        num[j] += __shfl_xor(num[j], 32, 64);
    }
    float rden = (den > 1e-30f) ? 1.f / den : 0.f;
    if (lane == 0) den_g[n] = den;
    if (g == 0) {
        float r[8];
#pragma unroll
        for (int j = 0; j < 8; ++j) {
            float v = num[j] * rden + bgat[c0 + j];
            r[j] = v > 0.f ? v : 0.f;
        }
        xr[(size_t)n * 16 + gl] = make_uint4(pack2(r[0], r[1]), pack2(r[2], r[3]),
                                             pack2(r[4], r[5]), pack2(r[6], r[7]));
    }
}

// ---------------------------------------------------------------------------
// GEMM1 (MFMA): hg = h @ W2; h bf16 rows (256 B), hg -> fp8 rows (128 B).
// ---------------------------------------------------------------------------
__global__ __launch_bounds__(256) void k_gemm1(
    const u32* __restrict__ hb, const float* __restrict__ W2,
    uint2* __restrict__ hg8)
{
    int lane = threadIdx.x & 63;
    int wv = threadIdx.x >> 6;
    int quad = lane >> 4;
    int l15 = lane & 15;

    // B fragments [kc][n0], once per block (W2 is L2-hot)
    bf16x8 bfrag[4][8];
#pragma unroll
    for (int kc = 0; kc < 4; ++kc) {
#pragma unroll
        for (int n0 = 0; n0 < 8; ++n0) {
            int kbase = kc * 32 + quad * 8;
            int col = n0 * 16 + l15;
            union { bf16x8 v; u32 u[4]; } t;
#pragma unroll
            for (int jj = 0; jj < 4; ++jj) {
                float w0 = W2[(kbase + 2 * jj) * CH + col];
                float w1 = W2[(kbase + 2 * jj + 1) * CH + col];
                t.u[jj] = pack2(w0, w1);
            }
            bfrag[kc][n0] = t.v;
        }
    }

    const int nchunk = (NN + 63) / 64;       // 1563
    for (int ch = blockIdx.x; ch < nchunk; ch += gridDim.x) {
        int m0 = ch * 64 + wv * 16;
        int arow = m0 + l15;
        if (arow >= NN) arow = NN - 1;       // clamp (stores guarded)
        const uint4* ap = (const uint4*)(hb + (size_t)arow * 64);

        bf16x8 afrag[4];
#pragma unroll
        for (int kc = 0; kc < 4; ++kc) {
            union { uint4 q; bf16x8 v; } t;
            t.q = ap[kc * 4 + quad];
            afrag[kc] = t.v;
        }

        f32x4 acc[8];
#pragma unroll
        for (int n0 = 0; n0 < 8; ++n0) acc[n0] = (f32x4){0.f, 0.f, 0.f, 0.f};
#pragma unroll
        for (int n0 = 0; n0 < 8; ++n0)
#pragma unroll
            for (int kc = 0; kc < 4; ++kc)
                acc[n0] = __builtin_amdgcn_mfma_f32_16x16x32_bf16(
                    afrag[kc], bfrag[kc][n0], acc[n0], 0, 0, 0);

#pragma unroll
        for (int r = 0; r < 4; ++r) {
            int row = m0 + quad * 4 + r;
            if (row < NN) {
                int a = pk_fp8<false>(acc[0][r], acc[1][r], 0);
                a = pk_fp8<true>(acc[2][r], acc[3][r], a);
                int b = pk_fp8<false>(acc[4][r], acc[5][r], 0);
                b = pk_fp8<true>(acc[6][r], acc[7][r], b);
                hg8[(size_t)row * 16 + l15] = make_uint2((u32)a, (u32)b);
            }
        }
    }
}

// ---------------------------------------------------------------------------
// k_h2f (wave/node; 4 edge-groups of 16), UNROLL x2 + LDS constants — the
// verified depth optimum (x1 baseline, x2 = -12 µs, x4 = +42 µs). NEW vs r13:
// erec loads are NON-TEMPORAL — the 27 MB read-once stream no longer evicts
// the reused hg8 gather lines (12.8 MB footprint vs 4 MB/XCD L2).
// ---------------------------------------------------------------------------
__global__ __launch_bounds__(256) void k_h2f(
    const u32* __restrict__ rowptr, const uint4* __restrict__ erec,
    const float* __restrict__ den_g, const uint2* __restrict__ hg8,
    const float* __restrict__ bgcn, const float* __restrict__ W3,
    const float* __restrict__ b3,
    float* __restrict__ out_alpha, float* __restrict__ out)
{
    __shared__ float sW30[CH], sW31[CH], sBg[CH];
    for (int i = threadIdx.x; i < CH; i += 256) {
        sW30[i] = W3[2 * i];
        sW31[i] = W3[2 * i + 1];
        sBg[i]  = bgcn[i];
    }
    __syncthreads();

    int n = (blockIdx.x << 2) + (threadIdx.x >> 6);
    int lane = threadIdx.x & 63;
    int g = lane >> 4;
    int gl = lane & 15;

    float dn = den_g[n];
    float rden = (dn > 1e-30f) ? 1.f / dn : 0.f;
    u32 p0 = rowptr[n], p1 = rowptr[n + 1];
    u32 last = p1 - 1;
    float acc[8] = {0.f, 0.f, 0.f, 0.f, 0.f, 0.f, 0.f, 0.f};

    u32 p = p0 + g;
    uint4 erA = nt_ld4(&erec[p      <= last ? p      : last]);
    uint4 erB = nt_ld4(&erec[p + 4  <= last ? p + 4  : last]);
    uint4 erC = nt_ld4(&erec[p + 8  <= last ? p + 8  : last]);
    uint4 erD = nt_ld4(&erec[p + 12 <= last ? p + 12 : last]);
    uint2 wA = hg8[(size_t)erA.x * 16 + gl];
    uint2 wB = hg8[(size_t)erB.x * 16 + gl];

    for (; p < p1; p += 8) {
        uint4 erE = nt_ld4(&erec[p + 16 <= last ? p + 16 : last]);  // prefetch
        uint4 erF = nt_ld4(&erec[p + 20 <= last ? p + 20 : last]);  // prefetch
        uint2 wC = hg8[(size_t)erC.x * 16 + gl];                    // prefetch
        uint2 wD = hg8[(size_t)erD.x * 16 + gl];                    // prefetch

        // ---- edge A (index p) ----
        {
            float a = __uint_as_float(erA.w) * rden;
            if (gl == 0) nt_stf(out_alpha + erA.z, a);
            f32x2 d0 = unpk_fp8<false>(wA.x), d1 = unpk_fp8<true>(wA.x);
            f32x2 d2 = unpk_fp8<false>(wA.y), d3 = unpk_fp8<true>(wA.y);
            acc[0] += a * d0.x; acc[1] += a * d0.y;
            acc[2] += a * d1.x; acc[3] += a * d1.y;
            acc[4] += a * d2.x; acc[5] += a * d2.y;
            acc[6] += a * d3.x; acc[7] += a * d3.y;
        }
        // ---- edge B (index p+4, guarded) ----
        {
            bool vB = (p + 4) < p1;
            float a = __uint_as_float(erB.w) * rden;
            a = vB ? a : 0.f;
            if (gl == 0 && vB) nt_stf(out_alpha + erB.z, a);
            f32x2 d0 = unpk_fp8<false>(wB.x), d1 = unpk_fp8<true>(wB.x);
            f32x2 d2 = unpk_fp8<false>(wB.y), d3 = unpk_fp8<true>(wB.y);
            acc[0] += a * d0.x; acc[1] += a * d0.y;
            acc[2] += a * d1.x; acc[3] += a * d1.y;
            acc[4] += a * d2.x; acc[5] += a * d2.y;
            acc[6] += a * d3.x; acc[7] += a * d3.y;
        }
        erA = erC; erB = erD; erC = erE; erD = erF; wA = wC; wB = wD;
    }
#pragma unroll
    for (int j = 0; j < 8; ++j) {
        acc[j] += __shfl_xor(acc[j], 16, 64);
        acc[j] += __shfl_xor(acc[j], 32, 64);
    }
    float o0 = 0.f, o1 = 0.f;
#pragma unroll
    for (int j = 0; j < 8; ++j) {
        int c = 16 * j + gl;
        float v = acc[j] + sBg[c];
        v = v > 0.f ? v : 0.f;
        o0 += v * sW30[c];
        o1 += v * sW31[c];
    }
    o0 += __shfl_xor(o0, 1, 64); o1 += __shfl_xor(o1, 1, 64);
    o0 += __shfl_xor(o0, 2, 64); o1 += __shfl_xor(o1, 2, 64);
    o0 += __shfl_xor(o0, 4, 64); o1 += __shfl_xor(o1, 4, 64);
    o0 += __shfl_xor(o0, 8, 64); o1 += __shfl_xor(o1, 8, 64);
    if (lane == 0) {
        out[n * 2]     = o0 + b3[0];
        out[n * 2 + 1] = o1 + b3[1];
    }
}

// ---------------------------------------------------------------------------
extern "C" void kernel_launch(void* const* d_in, const int* in_sizes, int n_in,
                              void* d_out, int out_size, void* d_ws, size_t ws_size,
                              hipStream_t stream)
{
    const float* x    = (const float*)d_in[0];
    const int*   ei   = (const int*)d_in[1];
    const float* ew   = (const float*)d_in[2];
    const float* Wl   = (const float*)d_in[3];
    const float* bl   = (const float*)d_in[4];
    const float* Wr   = (const float*)d_in[5];
    const float* br   = (const float*)d_in[6];
    const float* We   = (const float*)d_in[7];
    const float* att  = (const float*)d_in[8];
    const float* bgat = (const float*)d_in[9];
    const float* W2   = (const float*)d_in[10];
    const float* bgcn = (const float*)d_in[11];
    const float* W3   = (const float*)d_in[12];
    const float* b3   = (const float*)d_in[13];

    float* out       = (float*)d_out;          // chunk0: out [N,2] f32
    float* out_idx   = out + 200000;           // chunk1: stack([src,dst]) [2,ET]
    float* out_alpha = out + 200000 + 2 * ET;  // chunk2: alpha [ET,1]

    // workspace (~66.5 MB):
    // xl8 u32[NN*32] (fp8 xl; later hg8 fp8)  | xrh uint2[NN*32] (bf16 xr -> h)
    // | erec uint4[ET] | den f32[NN] | gcur u32[NBC*16] | rowptr[NN+1] | bbase[512]
    // stage uint4[NBC*BSTR] (33.6MB) + stage8 u8[NBC*BSTR] (2.1MB) alias
    // xl8+xrh (38.4MB), consumed by k_bucketB before k_pre writes.
    u32*   xl8    = (u32*)d_ws;
    uint2* xrh    = (uint2*)(xl8 + (size_t)NN * 32);
    uint4* erec   = (uint4*)(xrh + (size_t)NN * 32);
    float* den    = (float*)(erec + ET);
    u32*   gcur   = (u32*)den + NN;
    u32*   rowptr = gcur + NBC * 16;
    u32*   bbase  = rowptr + NN + 1;
    uint4* stage  = (uint4*)d_ws;                       // alias: xl8/xrh region
    u8*    stage8 = (u8*)d_ws + (size_t)NBC * BSTR * 16;  // after stage, still in alias

    const int AB = (ET + PA_EPB - 1) / PA_EPB; // 831

    // --- CSR build (+ out_idx): bucketA -> scanG -> bucketB (writes rowptr) ---
    (void)hipMemsetAsync(gcur, 0, NBC * 16 * sizeof(u32), stream);
    k_bucketA<<<AB, 256, 0, stream>>>(ei, ew, gcur, stage, stage8, out_idx);
    k_scanG<<<1, 512, 0, stream>>>(gcur, bbase, rowptr);
    k_bucketB<<<NBC, 256, 0, stream>>>(gcur, bbase, stage, stage8, rowptr, erec);

    // --- projections + fused attention/aggregation ---
    k_pre<<<(NN * 32) / 256, 256, 0, stream>>>(x, Wl, bl, Wr, br, xl8, xrh);
    k_fused<<<NN / 4, 256, 0, stream>>>(rowptr, erec, xl8, We, att, bgat,
                                        (uint4*)xrh, den);

    // --- GCN (MFMA, fp8 out) + fused h2+MLP ---
    k_gemm1<<<512, 256, 0, stream>>>((const u32*)xrh, W2, (uint2*)xl8);
    k_h2f<<<NN / 4, 256, 0, stream>>>(rowptr, erec, den, (const uint2*)xl8,
                                      bgcn, W3, b3, out_alpha, out);
}

// Round 16
// 368.559 us; speedup vs baseline: 1.1170x; 1.0623x over previous
//
#include <hip/hip_runtime.h>
#include <hip/hip_bf16.h>

#define NN 100000     // nodes
#define NE 1600000    // edges before self loops
#define ET 1700000    // NE + NN
#define CH 128        // hidden channels (H*C, H=1)
#define NBC 391       // coarse buckets of 256 dst-nodes
#define PA_EPB 2048   // edges per block, phase A
#define BSTR 5376     // stage stride per bucket (mean 4352 + 15.5 sigma)

typedef unsigned int u32;
typedef unsigned short u16;
typedef unsigned char u8;

typedef __attribute__((ext_vector_type(8))) short bf16x8;
typedef __attribute__((ext_vector_type(4))) float f32x4;
typedef __attribute__((ext_vector_type(2))) float f32x2;

__device__ __forceinline__ float lo2f(u32 w) { return __uint_as_float(w << 16); }
__device__ __forceinline__ float hi2f(u32 w) { return __uint_as_float(w & 0xFFFF0000u); }
__device__ __forceinline__ u32 f2bits(float v) {
    __hip_bfloat16 t = __float2bfloat16(v);
    return (u32)*(u16*)&t;
}
__device__ __forceinline__ u32 pack2(float a, float b) {
    return (f2bits(b) << 16) | f2bits(a);
}
// fp8 e4m3 HW converts — word-select must be a compile-time constant
template<bool HI>
__device__ __forceinline__ int pk_fp8(float a, float b, int old) {
    return __builtin_amdgcn_cvt_pk_fp8_f32(a, b, old, HI);
}
template<bool HI>
__device__ __forceinline__ f32x2 unpk_fp8(u32 w) {
    return __builtin_amdgcn_cvt_pk_f32_fp8((int)w, HI);
}

// non-temporal (L2 no-allocate) streaming access — use ONLY for data that is
// never re-read (r15 lesson: nt bypasses L3 too; erec/xl8/hg8 are L3-resident)
__device__ __forceinline__ int nt_ld(const int* p) { return __builtin_nontemporal_load(p); }
__device__ __forceinline__ float nt_ldf(const float* p) { return __builtin_nontemporal_load(p); }
__device__ __forceinline__ void nt_stf(float* p, float v) { __builtin_nontemporal_store(v, p); }

// ---------------------------------------------------------------------------
// Phase A: LDS-aggregated coarse bucketing into FIXED-stride bucket regions.
// ---------------------------------------------------------------------------
__global__ __launch_bounds__(256) void k_bucketA(
    const int* __restrict__ ei, const float* __restrict__ ew,
    u32* __restrict__ gcur, uint4* __restrict__ stage,
    u8* __restrict__ stage8, float* __restrict__ out_idx)
{
    __shared__ u32 hist[NBC];
    __shared__ u32 gbase[NBC];
    for (int i = threadIdx.x; i < NBC; i += 256) hist[i] = 0u;
    __syncthreads();
    int e0 = blockIdx.x * PA_EPB;
    int sA[8], dA[8], cbA[8];
    float w0A[8], w1A[8];
    u32 rkA[8];
#pragma unroll
    for (int i = 0; i < 8; ++i) {
        int e = e0 + i * 256 + threadIdx.x;
        int s = 0, d = 0; float w0 = 0.f, w1 = 0.f;
        if (e < ET) {
            if (e < NE) {
                s = nt_ld(ei + e); d = nt_ld(ei + NE + e);
                w0 = nt_ldf(ew + 2 * e); w1 = nt_ldf(ew + 2 * e + 1);
            } else { s = d = e - NE; }
            nt_stf(out_idx + e,      (float)s);
            nt_stf(out_idx + ET + e, (float)d);
            if ((u32)d >= NN) d = 0;
            if ((u32)s >= NN) s = 0;
            int cb = d >> 8;
            rkA[i] = atomicAdd(&hist[cb], 1u);
            cbA[i] = cb;
        } else cbA[i] = -1;
        sA[i] = s; dA[i] = d; w0A[i] = w0; w1A[i] = w1;
    }
    __syncthreads();
    for (int i = threadIdx.x; i < NBC; i += 256) {
        u32 h = hist[i];
        gbase[i] = h ? atomicAdd(&gcur[i * 16], h) : 0u;   // 64B-padded cursors
    }
    __syncthreads();
#pragma unroll
    for (int i = 0; i < 8; ++i) {
        if (cbA[i] < 0) continue;
        int e = e0 + i * 256 + threadIdx.x;
        u32 pos = (u32)cbA[i] * BSTR + gbase[cbA[i]] + rkA[i];
        stage[pos]  = make_uint4((u32)sA[i], pack2(w0A[i], w1A[i]), (u32)e, (u32)dA[i]);
        stage8[pos] = (u8)(dA[i] & 255);
    }
}

// ---------------------------------------------------------------------------
// scanG: one block scans the 391 bucket totals (gcur) -> bucket bases (bbase).
// ---------------------------------------------------------------------------
__global__ __launch_bounds__(512) void k_scanG(
    const u32* __restrict__ gcur, u32* __restrict__ bbase,
    u32* __restrict__ rowptr)
{
    __shared__ u32 s[512];
    int t = threadIdx.x;
    u32 v = (t < NBC) ? gcur[t * 16] : 0u;
    s[t] = v; __syncthreads();
    for (int off = 1; off < 512; off <<= 1) {
        u32 a = (t >= off) ? s[t - off] : 0u;
        __syncthreads();
        s[t] += a;
        __syncthreads();
    }
    if (t < NBC) bbase[t] = s[t] - v;    // exclusive bucket base
    if (t == 0) rowptr[NN] = ET;
}

// ---------------------------------------------------------------------------
// Phase B: one block per bucket; histogram -> rowptr -> scatter.
// ---------------------------------------------------------------------------
__global__ __launch_bounds__(256) void k_bucketB(
    const u32* __restrict__ gcur, const u32* __restrict__ bbase,
    const uint4* __restrict__ stage, const u8* __restrict__ stage8,
    u32* __restrict__ rowptr, uint4* __restrict__ erec)
{
    __shared__ u32 hist[256];
    __shared__ u32 cur[256];
    int b = blockIdx.x;
    u32 cnt_b = gcur[b * 16];
    u32 bb = bbase[b];
    const uint4* sb = stage + (size_t)b * BSTR;
    const u8*    s8 = stage8 + (size_t)b * BSTR;

    hist[threadIdx.x] = 0u;
    __syncthreads();
    for (u32 p = threadIdx.x; p < cnt_b; p += 256)
        atomicAdd(&hist[s8[p]], 1u);
    __syncthreads();
    u32 v = hist[threadIdx.x];
    for (int off = 1; off < 256; off <<= 1) {
        u32 a = (threadIdx.x >= off) ? hist[threadIdx.x - off] : 0u;
        __syncthreads();
        hist[threadIdx.x] += a;
        __syncthreads();
    }
    u32 start = bb + hist[threadIdx.x] - v;    // exclusive
    int n = (b << 8) + threadIdx.x;
    if (n < NN) rowptr[n] = start;
    cur[threadIdx.x] = start;
    __syncthreads();
    for (u32 p = threadIdx.x; p < cnt_b; p += 256) {
        uint4 r = sb[p];
        u32 slot = atomicAdd(&cur[r.w & 255], 1u);
        erec[slot] = make_uint4(r.x, r.y, r.z, 0u);
    }
}

// ---------------------------------------------------------------------------
// k_pre: xl = x@Wl+bl -> fp8 (128 B/row); xr = x@Wr+br -> bf16 (256 B/row)
// ---------------------------------------------------------------------------
__global__ __launch_bounds__(256) void k_pre(
    const float* __restrict__ x,
    const float* __restrict__ Wl, const float* __restrict__ bl,
    const float* __restrict__ Wr, const float* __restrict__ br,
    u32* __restrict__ xl8, uint2* __restrict__ xrh)
{
    __shared__ float sWl[6][CH], sWr[6][CH], sbl[CH], sbr[CH];
    for (int i = threadIdx.x; i < 6 * CH; i += 256) {
        sWl[i / CH][i % CH] = Wl[i];
        sWr[i / CH][i % CH] = Wr[i];
    }
    for (int i = threadIdx.x; i < CH; i += 256) { sbl[i] = bl[i]; sbr[i] = br[i]; }
    __syncthreads();

    int tid = blockIdx.x * 256 + threadIdx.x;   // grid covers NN*32 exactly
    int n = tid >> 5, q = tid & 31, c0 = q * 4;
    float xs[6];
#pragma unroll
    for (int k = 0; k < 6; ++k) xs[k] = x[n * 6 + k];
    float l[4], r[4];
#pragma unroll
    for (int j = 0; j < 4; ++j) { l[j] = sbl[c0 + j]; r[j] = sbr[c0 + j]; }
#pragma unroll
    for (int k = 0; k < 6; ++k)
#pragma unroll
        for (int j = 0; j < 4; ++j) {
            l[j] += xs[k] * sWl[k][c0 + j];
            r[j] += xs[k] * sWr[k][c0 + j];
        }
    int v = pk_fp8<false>(l[0], l[1], 0);
    v = pk_fp8<true>(l[2], l[3], v);
    xl8[tid] = (u32)v;                               // bytes = channels c0..c0+3
    xrh[tid] = make_uint2(pack2(r[0], r[1]), pack2(r[2], r[3]));
}

// ---------------------------------------------------------------------------
// k_fused (wave/node; 4 edge-groups of 16 lanes x 8 channels), depth-2
// software pipeline — round-3 verified body (121.5 µs, 48 VGPR, occ 47.5%).
// DO NOT TOUCH: r6/r7/r9/r10/r12 all regressed or washed. 48 VGPR is the
// last slot in the good occupancy tier.
// ---------------------------------------------------------------------------
__global__ __launch_bounds__(256) void k_fused(
    const u32* __restrict__ rowptr, uint4* erec,
    const u32* __restrict__ xl8,
    const float* __restrict__ We, const float* __restrict__ att,
    const float* __restrict__ bgat,
    uint4* xr,                        // in: xr bf16 ; out: h bf16 (in place)
    float* __restrict__ den_g)
{
    int n = (blockIdx.x << 2) + (threadIdx.x >> 6);   // grid: NN/4
    int lane = threadIdx.x & 63;
    int g = lane >> 4;            // edge-group 0..3
    int gl = lane & 15;           // lane in group
    int c0 = gl * 8;              // 8 channels per lane

    float we0[8], we1[8], at[8];
#pragma unroll
    for (int j = 0; j < 8; ++j) {
        we0[j] = We[c0 + j];
        we1[j] = We[CH + c0 + j];
        at[j]  = att[c0 + j];
    }

    uint4 xw = xr[(size_t)n * 16 + gl];   // 8 bf16 channels
    float xrv[8] = {lo2f(xw.x), hi2f(xw.x), lo2f(xw.y), hi2f(xw.y),
                    lo2f(xw.z), hi2f(xw.z), lo2f(xw.w), hi2f(xw.w)};

    u32 p0 = rowptr[n], p1 = rowptr[n + 1];
    u32 last = p1 - 1;                    // >= p0 (self-loop guarantees >=1)
    float den = 0.f;
    float num[8] = {0.f, 0.f, 0.f, 0.f, 0.f, 0.f, 0.f, 0.f};

    u32 p = p0 + g;
    uint4 er0 = erec[p <= last ? p : last];
    uint4 er1 = erec[p + 4 <= last ? p + 4 : last];
    uint2 w0 = ((const uint2*)xl8)[(size_t)er0.x * 16 + gl];

    for (; p < p1; p += 4) {
        uint4 er2 = erec[p + 8 <= last ? p + 8 : last];             // prefetch
        uint2 w1 = ((const uint2*)xl8)[(size_t)er1.x * 16 + gl];    // prefetch
        float ea0 = lo2f(er0.y), ea1 = hi2f(er0.y);
        f32x2 d0 = unpk_fp8<false>(w0.x), d1 = unpk_fp8<true>(w0.x);
        f32x2 d2 = unpk_fp8<false>(w0.y), d3 = unpk_fp8<true>(w0.y);
        float xl[8] = {d0.x, d0.y, d1.x, d1.y, d2.x, d2.y, d3.x, d3.y};
        float s = 0.f;
#pragma unroll
        for (int j = 0; j < 8; ++j) {
            float z = xl[j] + xrv[j] + ea0 * we0[j] + ea1 * we1[j];
            z = z > 0.f ? z : 0.2f * z;         // leaky_relu(0.2)
            s += z * at[j];
        }
        s += __shfl_xor(s, 1, 64);
        s += __shfl_xor(s, 2, 64);
        s += __shfl_xor(s, 4, 64);
        s += __shfl_xor(s, 8, 64);              // all 16 lanes hold s
        s = fminf(fmaxf(s, -60.f), 60.f);
        float ex = __expf(s);
        den += ex;
#pragma unroll
        for (int j = 0; j < 8; ++j) num[j] += ex * xl[j];
        if (gl == 0) erec[p].w = __float_as_uint(ex);
        er0 = er1; er1 = er2; w0 = w1;
    }
    // cross-group merge
    den += __shfl_xor(den, 16, 64);
    den += __shfl_xor(den, 32, 64);
#pragma unroll
    for (int j = 0; j < 8; ++j) {
        num[j] += __shfl_xor(num[j], 16, 64);
        num[j] += __shfl_xor(num[j], 32, 64);
    }
    float rden = (den > 1e-30f) ? 1.f / den : 0.f;
    if (lane == 0) den_g[n] = den;
    if (g == 0) {
        float r[8];
#pragma unroll
        for (int j = 0; j < 8; ++j) {
            float v = num[j] * rden + bgat[c0 + j];
            r[j] = v > 0.f ? v : 0.f;
        }
        xr[(size_t)n * 16 + gl] = make_uint4(pack2(r[0], r[1]), pack2(r[2], r[3]),
                                             pack2(r[4], r[5]), pack2(r[6], r[7]));
    }
}

// ---------------------------------------------------------------------------
// GEMM1 (MFMA): hg = h @ W2; h bf16 rows (256 B), hg -> fp8 rows (128 B).
// ---------------------------------------------------------------------------
__global__ __launch_bounds__(256) void k_gemm1(
    const u32* __restrict__ hb, const float* __restrict__ W2,
    uint2* __restrict__ hg8)
{
    int lane = threadIdx.x & 63;
    int wv = threadIdx.x >> 6;
    int quad = lane >> 4;
    int l15 = lane & 15;

    // B fragments [kc][n0], once per block (W2 is L2-hot)
    bf16x8 bfrag[4][8];
#pragma unroll
    for (int kc = 0; kc < 4; ++kc) {
#pragma unroll
        for (int n0 = 0; n0 < 8; ++n0) {
            int kbase = kc * 32 + quad * 8;
            int col = n0 * 16 + l15;
            union { bf16x8 v; u32 u[4]; } t;
#pragma unroll
            for (int jj = 0; jj < 4; ++jj) {
                float w0 = W2[(kbase + 2 * jj) * CH + col];
                float w1 = W2[(kbase + 2 * jj + 1) * CH + col];
                t.u[jj] = pack2(w0, w1);
            }
            bfrag[kc][n0] = t.v;
        }
    }

    const int nchunk = (NN + 63) / 64;       // 1563
    for (int ch = blockIdx.x; ch < nchunk; ch += gridDim.x) {
        int m0 = ch * 64 + wv * 16;
        int arow = m0 + l15;
        if (arow >= NN) arow = NN - 1;       // clamp (stores guarded)
        const uint4* ap = (const uint4*)(hb + (size_t)arow * 64);

        bf16x8 afrag[4];
#pragma unroll
        for (int kc = 0; kc < 4; ++kc) {
            union { uint4 q; bf16x8 v; } t;
            t.q = ap[kc * 4 + quad];
            afrag[kc] = t.v;
        }

        f32x4 acc[8];
#pragma unroll
        for (int n0 = 0; n0 < 8; ++n0) acc[n0] = (f32x4){0.f, 0.f, 0.f, 0.f};
#pragma unroll
        for (int n0 = 0; n0 < 8; ++n0)
#pragma unroll
            for (int kc = 0; kc < 4; ++kc)
                acc[n0] = __builtin_amdgcn_mfma_f32_16x16x32_bf16(
                    afrag[kc], bfrag[kc][n0], acc[n0], 0, 0, 0);

#pragma unroll
        for (int r = 0; r < 4; ++r) {
            int row = m0 + quad * 4 + r;
            if (row < NN) {
                int a = pk_fp8<false>(acc[0][r], acc[1][r], 0);
                a = pk_fp8<true>(acc[2][r], acc[3][r], a);
                int b = pk_fp8<false>(acc[4][r], acc[5][r], 0);
                b = pk_fp8<true>(acc[6][r], acc[7][r], b);
                hg8[(size_t)row * 16 + l15] = make_uint2((u32)a, (u32)b);
            }
        }
    }
}

// ---------------------------------------------------------------------------
// k_h2f (wave/node; 4 edge-groups of 16), UNROLL x2 + LDS constants — the
// verified depth optimum (x1 baseline, x2 = -12 µs, x4 = +42 µs). Regular
// (cached) erec loads — erec is L3-resident; nt cost +22 µs (r15).
// ---------------------------------------------------------------------------
__global__ __launch_bounds__(256) void k_h2f(
    const u32* __restrict__ rowptr, const uint4* __restrict__ erec,
    const float* __restrict__ den_g, const uint2* __restrict__ hg8,
    const float* __restrict__ bgcn, const float* __restrict__ W3,
    const float* __restrict__ b3,
    float* __restrict__ out_alpha, float* __restrict__ out)
{
    __shared__ float sW30[CH], sW31[CH], sBg[CH];
    for (int i = threadIdx.x; i < CH; i += 256) {
        sW30[i] = W3[2 * i];
        sW31[i] = W3[2 * i + 1];
        sBg[i]  = bgcn[i];
    }
    __syncthreads();

    int n = (blockIdx.x << 2) + (threadIdx.x >> 6);
    int lane = threadIdx.x & 63;
    int g = lane >> 4;
    int gl = lane & 15;

    float dn = den_g[n];
    float rden = (dn > 1e-30f) ? 1.f / dn : 0.f;
    u32 p0 = rowptr[n], p1 = rowptr[n + 1];
    u32 last = p1 - 1;
    float acc[8] = {0.f, 0.f, 0.f, 0.f, 0.f, 0.f, 0.f, 0.f};

    u32 p = p0 + g;
    uint4 erA = erec[p      <= last ? p      : last];
    uint4 erB = erec[p + 4  <= last ? p + 4  : last];
    uint4 erC = erec[p + 8  <= last ? p + 8  : last];
    uint4 erD = erec[p + 12 <= last ? p + 12 : last];
    uint2 wA = hg8[(size_t)erA.x * 16 + gl];
    uint2 wB = hg8[(size_t)erB.x * 16 + gl];

    for (; p < p1; p += 8) {
        uint4 erE = erec[p + 16 <= last ? p + 16 : last];   // prefetch
        uint4 erF = erec[p + 20 <= last ? p + 20 : last];   // prefetch
        uint2 wC = hg8[(size_t)erC.x * 16 + gl];            // prefetch
        uint2 wD = hg8[(size_t)erD.x * 16 + gl];            // prefetch

        // ---- edge A (index p) ----
        {
            float a = __uint_as_float(erA.w) * rden;
            if (gl == 0) nt_stf(out_alpha + erA.z, a);
            f32x2 d0 = unpk_fp8<false>(wA.x), d1 = unpk_fp8<true>(wA.x);
            f32x2 d2 = unpk_fp8<false>(wA.y), d3 = unpk_fp8<true>(wA.y);
            acc[0] += a * d0.x; acc[1] += a * d0.y;
            acc[2] += a * d1.x; acc[3] += a * d1.y;
            acc[4] += a * d2.x; acc[5] += a * d2.y;
            acc[6] += a * d3.x; acc[7] += a * d3.y;
        }
        // ---- edge B (index p+4, guarded) ----
        {
            bool vB = (p + 4) < p1;
            float a = __uint_as_float(erB.w) * rden;
            a = vB ? a : 0.f;
            if (gl == 0 && vB) nt_stf(out_alpha + erB.z, a);
            f32x2 d0 = unpk_fp8<false>(wB.x), d1 = unpk_fp8<true>(wB.x);
            f32x2 d2 = unpk_fp8<false>(wB.y), d3 = unpk_fp8<true>(wB.y);
            acc[0] += a * d0.x; acc[1] += a * d0.y;
            acc[2] += a * d1.x; acc[3] += a * d1.y;
            acc[4] += a * d2.x; acc[5] += a * d2.y;
            acc[6] += a * d3.x; acc[7] += a * d3.y;
        }
        erA = erC; erB = erD; erC = erE; erD = erF; wA = wC; wB = wD;
    }
#pragma unroll
    for (int j = 0; j < 8; ++j) {
        acc[j] += __shfl_xor(acc[j], 16, 64);
        acc[j] += __shfl_xor(acc[j], 32, 64);
    }
    float o0 = 0.f, o1 = 0.f;
#pragma unroll
    for (int j = 0; j < 8; ++j) {
        int c = 16 * j + gl;
        float v = acc[j] + sBg[c];
        v = v > 0.f ? v : 0.f;
        o0 += v * sW30[c];
        o1 += v * sW31[c];
    }
    o0 += __shfl_xor(o0, 1, 64); o1 += __shfl_xor(o1, 1, 64);
    o0 += __shfl_xor(o0, 2, 64); o1 += __shfl_xor(o1, 2, 64);
    o0 += __shfl_xor(o0, 4, 64); o1 += __shfl_xor(o1, 4, 64);
    o0 += __shfl_xor(o0, 8, 64); o1 += __shfl_xor(o1, 8, 64);
    if (lane == 0) {
        out[n * 2]     = o0 + b3[0];
        out[n * 2 + 1] = o1 + b3[1];
    }
}

// ---------------------------------------------------------------------------
extern "C" void kernel_launch(void* const* d_in, const int* in_sizes, int n_in,
                              void* d_out, int out_size, void* d_ws, size_t ws_size,
                              hipStream_t stream)
{
    const float* x    = (const float*)d_in[0];
    const int*   ei   = (const int*)d_in[1];
    const float* ew   = (const float*)d_in[2];
    const float* Wl   = (const float*)d_in[3];
    const float* bl   = (const float*)d_in[4];
    const float* Wr   = (const float*)d_in[5];
    const float* br   = (const float*)d_in[6];
    const float* We   = (const float*)d_in[7];
    const float* att  = (const float*)d_in[8];
    const float* bgat = (const float*)d_in[9];
    const float* W2   = (const float*)d_in[10];
    const float* bgcn = (const float*)d_in[11];
    const float* W3   = (const float*)d_in[12];
    const float* b3   = (const float*)d_in[13];

    float* out       = (float*)d_out;          // chunk0: out [N,2] f32
    float* out_idx   = out + 200000;           // chunk1: stack([src,dst]) [2,ET]
    float* out_alpha = out + 200000 + 2 * ET;  // chunk2: alpha [ET,1]

    // workspace (~66.5 MB):
    // xl8 u32[NN*32] (fp8 xl; later hg8 fp8)  | xrh uint2[NN*32] (bf16 xr -> h)
    // | erec uint4[ET] | den f32[NN] | gcur u32[NBC*16] | rowptr[NN+1] | bbase[512]
    // stage uint4[NBC*BSTR] (33.6MB) + stage8 u8[NBC*BSTR] (2.1MB) alias
    // xl8+xrh (38.4MB), consumed by k_bucketB before k_pre writes.
    u32*   xl8    = (u32*)d_ws;
    uint2* xrh    = (uint2*)(xl8 + (size_t)NN * 32);
    uint4* erec   = (uint4*)(xrh + (size_t)NN * 32);
    float* den    = (float*)(erec + ET);
    u32*   gcur   = (u32*)den + NN;
    u32*   rowptr = gcur + NBC * 16;
    u32*   bbase  = rowptr + NN + 1;
    uint4* stage  = (uint4*)d_ws;                       // alias: xl8/xrh region
    u8*    stage8 = (u8*)d_ws + (size_t)NBC * BSTR * 16;  // after stage, still in alias

    const int AB = (ET + PA_EPB - 1) / PA_EPB; // 831

    // --- CSR build (+ out_idx): bucketA -> scanG -> bucketB (writes rowptr) ---
    (void)hipMemsetAsync(gcur, 0, NBC * 16 * sizeof(u32), stream);
    k_bucketA<<<AB, 256, 0, stream>>>(ei, ew, gcur, stage, stage8, out_idx);
    k_scanG<<<1, 512, 0, stream>>>(gcur, bbase, rowptr);
    k_bucketB<<<NBC, 256, 0, stream>>>(gcur, bbase, stage, stage8, rowptr, erec);

    // --- projections + fused attention/aggregation ---
    k_pre<<<(NN * 32) / 256, 256, 0, stream>>>(x, Wl, bl, Wr, br, xl8, xrh);
    k_fused<<<NN / 4, 256, 0, stream>>>(rowptr, erec, xl8, We, att, bgat,
                                        (uint4*)xrh, den);

    // --- GCN (MFMA, fp8 out) + fused h2+MLP ---
    k_gemm1<<<512, 256, 0, stream>>>((const u32*)xrh, W2, (uint2*)xl8);
    k_h2f<<<NN / 4, 256, 0, stream>>>(rowptr, erec, den, (const uint2*)xl8,
                                      bgcn, W3, b3, out_alpha, out);
}